// Round 7
// baseline (176.372 us; speedup 1.0000x reference)
//
#include <hip/hip_runtime.h>
#include <hip/hip_bf16.h>

// MultiHeadedSelfAttention: N=2, S=2048, D=1024, H=16, DH=64, fp32 in/out.
// Round 7 (identical to rounds 5/6; both prior benches were infra failures):
//   qkv_proj: 1536 blocks = (nh:32, sb:16, mat:3). Block stages X(128x64) +
//             one W(64x64) as bf16 -> 16 MFMA. Q/K transposed form, V direct.
//             Q pre-scaled by log2(e)/8 (exp2 softmax domain).
//   attn:     1024 blocks x 4 waves, 16 q per wave (4096 waves, 4 blk/CU).
//             S^T = K Q^T; softmax per q-column in-register (+2 shfl);
//             P in per-wave LDS with the K/V chunk-XOR swizzle (round-2
//             verified conflict-free); wave-uniform rescale-skip guard;
//             O^T = V^T P^T; exp2f throughout.

#define NB 2
#define SS 2048
#define DM 1024
#define NH 16
#define DHd 64

typedef __attribute__((ext_vector_type(8))) short bf16x8;   // 8 bf16 = 4 VGPRs
typedef __attribute__((ext_vector_type(4))) float f32x4;

__device__ __forceinline__ unsigned short f2b(float x) {
    __hip_bfloat16 h = __float2bfloat16(x);
    return *reinterpret_cast<unsigned short*>(&h);
}

__device__ __forceinline__ ushort4 pack4f(float a, float b, float c, float d) {
    ushort4 r; r.x = f2b(a); r.y = f2b(b); r.z = f2b(c); r.w = f2b(d);
    return r;
}

__device__ __forceinline__ bf16x8 pack8(float4 a, float4 b) {
    union { bf16x8 v; unsigned short u[8]; } t;
    t.u[0] = f2b(a.x); t.u[1] = f2b(a.y); t.u[2] = f2b(a.z); t.u[3] = f2b(a.w);
    t.u[4] = f2b(b.x); t.u[5] = f2b(b.y); t.u[6] = f2b(b.z); t.u[7] = f2b(b.w);
    return t.v;
}

// [rows][64] bf16 tile, 16B-chunk XOR swizzle (0 conflicts measured, round 2)
__device__ __forceinline__ int swz(int row, int ch) {
    return row * 64 + ((ch ^ (row & 7)) * 8);
}

#define QSCALE 0.18033688011112042f   // (1/8) * log2(e)

__global__ __launch_bounds__(256) void qkv_proj(
    const float* __restrict__ seq,
    const float* __restrict__ Wq, const float* __restrict__ bq,
    const float* __restrict__ Wk, const float* __restrict__ bk,
    const float* __restrict__ Wv, const float* __restrict__ bv,
    unsigned short* __restrict__ Q, unsigned short* __restrict__ K,
    unsigned short* __restrict__ Vt)
{
    __shared__ unsigned short Xl[128 * 64];   // 16 KB
    __shared__ unsigned short Wl[64 * 64];    // 8 KB

    const int tid = threadIdx.x;
    const int wv = tid >> 6, L = tid & 63, lo = L & 15, qd = L >> 4;
    const int mat = blockIdx.x >> 9;          // 0:Q 1:K 2:V
    const int rem = blockIdx.x & 511;
    const int nh = rem >> 4, sb = rem & 15;
    const int h = nh & (NH - 1), n = nh >> 4;
    const int s0 = sb * 128;

    const float* Wm = (mat == 0) ? Wq : (mat == 1) ? Wk : Wv;
    const float* bm = (mat == 0) ? bq : (mat == 1) ? bk : bv;

    // ---- stage X tile (fp32 -> bf16, swizzled) ----
#pragma unroll
    for (int i = 0; i < 4; ++i) {
        int idx = tid + i * 256;
        int r = idx >> 3, ch = idx & 7;
        const float* src = seq + ((size_t)(n * SS + s0 + r)) * DM + h * DHd + ch * 8;
        float4 a = ((const float4*)src)[0];
        float4 b = ((const float4*)src)[1];
        *(bf16x8*)&Xl[swz(r, ch)] = pack8(a, b);
    }
    // ---- stage this block's W (fp32 -> bf16, swizzled) ----
#pragma unroll
    for (int i = 0; i < 2; ++i) {
        int idx = tid + i * 256;
        int e = idx >> 3, ch = idx & 7;
        const float* src = Wm + (size_t)(h * DHd + e) * DHd + ch * 8;
        float4 a = ((const float4*)src)[0];
        float4 b = ((const float4*)src)[1];
        *(bf16x8*)&Wl[swz(e, ch)] = pack8(a, b);
    }
    __syncthreads();

    // X fragments: rows wv*32 + st*16 + lo
    bf16x8 xf[2][2];
#pragma unroll
    for (int st = 0; st < 2; ++st)
#pragma unroll
        for (int kt = 0; kt < 2; ++kt)
            xf[st][kt] = *(const bf16x8*)&Xl[swz(wv * 32 + st * 16 + lo, kt * 4 + qd)];

    if (mat < 2) {
        // ---- Q/K transposed form: C row = e = et*16+qd*4+reg, col = s ----
        unsigned short* O = mat ? K : Q;
        const float sc = mat ? 1.0f : QSCALE;

        f32x4 acc[4][2];
#pragma unroll
        for (int et = 0; et < 4; ++et) {
            float4 bb = *(const float4*)&bm[h * DHd + et * 16 + qd * 4];
#pragma unroll
            for (int st = 0; st < 2; ++st)
                acc[et][st] = (f32x4){bb.x, bb.y, bb.z, bb.w};
        }
#pragma unroll
        for (int et = 0; et < 4; ++et) {
            bf16x8 wf0 = *(const bf16x8*)&Wl[swz(et * 16 + lo, qd)];
            bf16x8 wf1 = *(const bf16x8*)&Wl[swz(et * 16 + lo, 4 + qd)];
#pragma unroll
            for (int st = 0; st < 2; ++st) {
                acc[et][st] = __builtin_amdgcn_mfma_f32_16x16x32_bf16(
                    wf0, xf[st][0], acc[et][st], 0, 0, 0);
                acc[et][st] = __builtin_amdgcn_mfma_f32_16x16x32_bf16(
                    wf1, xf[st][1], acc[et][st], 0, 0, 0);
            }
        }
#pragma unroll
        for (int et = 0; et < 4; ++et)
#pragma unroll
            for (int st = 0; st < 2; ++st) {
                int s = s0 + wv * 32 + st * 16 + lo;
                ushort4 w = pack4f(acc[et][st][0] * sc, acc[et][st][1] * sc,
                                   acc[et][st][2] * sc, acc[et][st][3] * sc);
                *(ushort4*)&O[((size_t)nh * SS + s) * DHd + et * 16 + qd * 4] = w;
            }
    } else {
        // ---- V direct form: C row = s = st*16+qd*4+reg, col = e = et*16+lo ----
        float bvv[4];
#pragma unroll
        for (int et = 0; et < 4; ++et) bvv[et] = bm[h * DHd + et * 16 + lo];

        f32x4 acc[2][4];
#pragma unroll
        for (int st = 0; st < 2; ++st)
#pragma unroll
            for (int et = 0; et < 4; ++et)
                acc[st][et] = (f32x4){bvv[et], bvv[et], bvv[et], bvv[et]};
#pragma unroll
        for (int et = 0; et < 4; ++et) {
            bf16x8 wf0 = *(const bf16x8*)&Wl[swz(et * 16 + lo, qd)];
            bf16x8 wf1 = *(const bf16x8*)&Wl[swz(et * 16 + lo, 4 + qd)];
#pragma unroll
            for (int st = 0; st < 2; ++st) {
                acc[st][et] = __builtin_amdgcn_mfma_f32_16x16x32_bf16(
                    xf[st][0], wf0, acc[st][et], 0, 0, 0);
                acc[st][et] = __builtin_amdgcn_mfma_f32_16x16x32_bf16(
                    xf[st][1], wf1, acc[st][et], 0, 0, 0);
            }
        }
#pragma unroll
        for (int st = 0; st < 2; ++st)
#pragma unroll
            for (int et = 0; et < 4; ++et) {
                int e = et * 16 + lo;
                int s = s0 + wv * 32 + st * 16 + qd * 4;
                ushort4 w = pack4f(acc[st][et][0], acc[st][et][1],
                                   acc[st][et][2], acc[st][et][3]);
                *(ushort4*)&Vt[((size_t)nh * DHd + e) * SS + s] = w;
            }
    }
}

__global__ __launch_bounds__(256) void attn(
    const unsigned short* __restrict__ Qg, const unsigned short* __restrict__ Kg,
    const unsigned short* __restrict__ Vg, float* __restrict__ out)
{
    __shared__ unsigned short Kl[64 * 64];      // [key][dh]  8 KB
    __shared__ unsigned short Vl[64 * 64];      // [dh][key]  8 KB
    __shared__ unsigned short Pl[4][16 * 64];   // per-wave [q][key] 8 KB

    const int tid = threadIdx.x;
    const int wv = tid >> 6, L = tid & 63, lo = L & 15, qd = L >> 4;
    const int bi = blockIdx.x;
    const int nh = bi >> 5, qblk = bi & 31;
    const int h = nh & (NH - 1), n = nh >> 4;
    const int q0 = qblk * 64 + wv * 16;         // wave's 16 queries

    const unsigned short* Qnh = Qg + (size_t)nh * SS * DHd;
    const unsigned short* Knh = Kg + (size_t)nh * SS * DHd;
    const unsigned short* Vnh = Vg + (size_t)nh * DHd * SS;   // [dh][s]

    // Q as B-operand: B[n=q=lo][k=dh=kt*32+qd*8+j]
    bf16x8 qf[2];
#pragma unroll
    for (int kt = 0; kt < 2; ++kt)
        qf[kt] = *(const bf16x8*)(Qnh + (size_t)(q0 + lo) * DHd + kt * 32 + qd * 8);

    f32x4 oacc[4];             // O^T: row = dh = rt*16+qd*4+reg, col = q = lo
#pragma unroll
    for (int rt = 0; rt < 4; ++rt) oacc[rt] = (f32x4){0.f, 0.f, 0.f, 0.f};

    float m = -1e30f, l = 0.f;

    for (int kv0 = 0; kv0 < SS; kv0 += 64) {
        __syncthreads();
#pragma unroll
        for (int i = 0; i < 2; ++i) {
            int idx = tid + i * 256;
            int r = idx >> 3, ch = idx & 7;
            *(uint4*)&Kl[swz(r, ch)] =
                *(const uint4*)(Knh + (size_t)(kv0 + r) * DHd + ch * 8);
            *(uint4*)&Vl[swz(r, ch)] =
                *(const uint4*)(Vnh + (size_t)r * SS + kv0 + ch * 8);
        }
        __syncthreads();

        // ---- S^T = K Q^T : C[row=key=rt*16+qd*4+reg][col=q=lo] ----
        f32x4 sacc[4];
#pragma unroll
        for (int rt = 0; rt < 4; ++rt) sacc[rt] = (f32x4){0.f, 0.f, 0.f, 0.f};
#pragma unroll
        for (int rt = 0; rt < 4; ++rt)
#pragma unroll
            for (int kt = 0; kt < 2; ++kt) {
                bf16x8 kf = *(const bf16x8*)&Kl[swz(rt * 16 + lo, kt * 4 + qd)];
                sacc[rt] = __builtin_amdgcn_mfma_f32_16x16x32_bf16(
                    kf, qf[kt], sacc[rt], 0, 0, 0);
            }

        // ---- online softmax for this q column (scores in log2 domain) ----
        float mx = sacc[0][0];
#pragma unroll
        for (int rt = 0; rt < 4; ++rt)
#pragma unroll
            for (int r = 0; r < 4; ++r) mx = fmaxf(mx, sacc[rt][r]);
        mx = fmaxf(mx, __shfl_xor(mx, 16, 64));
        mx = fmaxf(mx, __shfl_xor(mx, 32, 64));
        const float mn = fmaxf(m, mx);
        const bool up = __any(mn > m);          // wave-uniform guard

        float rs = 0.f;
#pragma unroll
        for (int rt = 0; rt < 4; ++rt) {
            float p0 = exp2f(sacc[rt][0] - mn);
            float p1 = exp2f(sacc[rt][1] - mn);
            float p2 = exp2f(sacc[rt][2] - mn);
            float p3 = exp2f(sacc[rt][3] - mn);
            rs += (p0 + p1) + (p2 + p3);
            // P[q=lo][key=rt*16+qd*4 .. +3]: chunk = 2rt+(qd>>1), sub = (qd&1)*4
            *(ushort4*)&Pl[wv][swz(lo, 2 * rt + (qd >> 1)) + (qd & 1) * 4] =
                pack4f(p0, p1, p2, p3);
        }
        rs += __shfl_xor(rs, 16, 64);
        rs += __shfl_xor(rs, 32, 64);

        if (up) {                               // max moved: rescale (rare)
            const float corr = exp2f(m - mn);
            l *= corr;
#pragma unroll
            for (int rt = 0; rt < 4; ++rt)
#pragma unroll
                for (int r = 0; r < 4; ++r) oacc[rt][r] *= corr;
            m = mn;
        }
        l += rs;

        // ---- O^T += V^T P^T : A=V^T[dh][key], B=P^T[key][q] ----
#pragma unroll
        for (int kt = 0; kt < 2; ++kt) {
            bf16x8 pf = *(const bf16x8*)&Pl[wv][swz(lo, kt * 4 + qd)];
#pragma unroll
            for (int rt = 0; rt < 4; ++rt) {
                bf16x8 vf = *(const bf16x8*)&Vl[swz(rt * 16 + lo, kt * 4 + qd)];
                oacc[rt] = __builtin_amdgcn_mfma_f32_16x16x32_bf16(
                    vf, pf, oacc[rt], 0, 0, 0);
            }
        }
    }

    // ---- epilogue: lane holds O^T[dh=rt*16+qd*4+reg][q=lo] ----
    const float inv = 1.0f / l;
    const int s = q0 + lo;
#pragma unroll
    for (int rt = 0; rt < 4; ++rt) {
        float4 o;
        o.x = oacc[rt][0] * inv; o.y = oacc[rt][1] * inv;
        o.z = oacc[rt][2] * inv; o.w = oacc[rt][3] * inv;
        *(float4*)&out[((size_t)n * SS + s) * DM + h * DHd + rt * 16 + qd * 4] = o;
    }
}

extern "C" void kernel_launch(void* const* d_in, const int* in_sizes, int n_in,
                              void* d_out, int out_size, void* d_ws, size_t ws_size,
                              hipStream_t stream) {
    const float* seq = (const float*)d_in[0];
    const float* Wq  = (const float*)d_in[1];
    const float* bq  = (const float*)d_in[2];
    const float* Wk  = (const float*)d_in[3];
    const float* bk  = (const float*)d_in[4];
    const float* Wv  = (const float*)d_in[5];
    const float* bv  = (const float*)d_in[6];
    float* out = (float*)d_out;

    const size_t per = (size_t)NB * NH * SS * DHd;  // 4.19M bf16 = 8.4 MB each
    unsigned short* Q  = (unsigned short*)d_ws;
    unsigned short* K  = Q + per;
    unsigned short* Vt = K + per;

    qkv_proj<<<1536, 256, 0, stream>>>(seq, Wq, bq, Wk, bk, Wv, bv, Q, K, Vt);
    attn<<<1024, 256, 0, stream>>>(Q, K, Vt, out);
}